// Round 3
// baseline (375.395 us; speedup 1.0000x reference)
//
#include <hip/hip_runtime.h>
#include <hip/hip_bf16.h>
#include <math.h>

// Problem: B=4, C=256, H=W=64 (N=4096), IC=128. I/O float32.
// Internal: split-bf16 (hi+lo) MFMA for precision-critical GEMMs.
typedef unsigned short ushort_t;
typedef __attribute__((ext_vector_type(8))) short   short8;   // bf16x8 MFMA frag
typedef __attribute__((ext_vector_type(8))) unsigned short ushort8;
typedef __attribute__((ext_vector_type(4))) float   float4v;

__device__ __forceinline__ float b2f(ushort_t u) {
    return __uint_as_float(((unsigned)u) << 16);
}
__device__ __forceinline__ ushort_t f2b(float f) {
    unsigned i = __float_as_uint(f);
    return (ushort_t)((i + 0x7FFFu + ((i >> 16) & 1u)) >> 16);  // RNE
}
__device__ __forceinline__ void split2(float v, ushort_t& h, ushort_t& l) {
    h = f2b(v);
    l = f2b(v - b2f(h));   // exact residual; combined rel err ~2^-17
}

// ---- workspace layout (bytes) ----
#define WTFH_OFF   0            // 192 KB  proj weights B-frag, hi
#define WTFL_OFF   196608       // 192 KB  lo
#define WWBH_OFF   393216       // 64 KB   w_w row-major bf16 hi
#define WWBL_OFF   458752       // 64 KB   lo
#define BIAS_OFF   524288       // 384 f32
#define STATS_OFF  526336       // 512 f32 (sum[256], sumsq[256])
#define PROJH_OFF  1048576      // B*N*256 bf16 = 8 MB (theta|phi), hi
#define PROJL_OFF  9437184      // 8 MB, lo
#define GT_OFF     17825792     // B*128*N bf16 = 4 MB (g transposed [b][ic][n])
#define Y2H_OFF    22020096     // B*N*128 bf16 = 4 MB, hi
#define Y2L_OFF    26214400     // 4 MB, lo
#define WY_OFF     30408704     // B*256*N bf16 = 8 MB
// total ~37 MB

// ============================================================================
// Kernel 1: proj-weight swizzle to B-frag order, split hi/lo; w_w split; bias;
// stats=0. WTf[((ot*8+kk)*64+lane)*8+j] = W_all[ot*16+(lane&15)][kk*32+(lane>>4)*8+j]
// o in [0,128): dx; [128,256): dy; [256,384): g
// ============================================================================
__global__ void prep_k(const float* __restrict__ dx_w, const float* __restrict__ dy_w,
                       const float* __restrict__ g_w,  const float* __restrict__ dx_b,
                       const float* __restrict__ dy_b, const float* __restrict__ g_b,
                       const float* __restrict__ w_w,
                       ushort_t* __restrict__ wtfh, ushort_t* __restrict__ wtfl,
                       ushort_t* __restrict__ wwbh, ushort_t* __restrict__ wwbl,
                       float* __restrict__ bias, float* __restrict__ stats) {
    int idx = blockIdx.x * 256 + threadIdx.x;          // 0..98303
    int j = idx & 7, lane = (idx >> 3) & 63, kk = (idx >> 9) & 7, ot = idx >> 12;
    int o = ot * 16 + (lane & 15);
    int c = kk * 32 + ((lane >> 4) * 8) + j;
    float v;
    if (o < 128)      v = dx_w[o * 256 + c];
    else if (o < 256) v = dy_w[(o - 128) * 256 + c];
    else              v = g_w[(o - 256) * 256 + c];
    ushort_t h, l;
    split2(v, h, l);
    wtfh[idx] = h; wtfl[idx] = l;
    if (idx < 32768) {                                 // w_w [256][128] row-major
        split2(w_w[idx], h, l);
        wwbh[idx] = h; wwbl[idx] = l;
    }
    if (idx < 384) {
        bias[idx] = (idx < 128) ? dx_b[idx]
                  : (idx < 256) ? dy_b[idx - 128]
                                : g_b[idx - 256];
    }
    if (idx < 512) stats[idx] = 0.f;                   // ws is 0xAA-poisoned each call
}

// ============================================================================
// Kernel 2: projections, split precision. Per block: (b, 64-row n-tile).
// Two passes over LDS (hi+lo of one source = 64KB): pass0 = x -> theta,
// pass1 = y -> phi, g. acc = Ah*Bh + Ah*Bl + Al*Bh.
// ============================================================================
__global__ __launch_bounds__(256) void proj_k(const float* __restrict__ x,
                                              const float* __restrict__ y,
                                              const ushort_t* __restrict__ wtfh,
                                              const ushort_t* __restrict__ wtfl,
                                              const float* __restrict__ bias,
                                              ushort_t* __restrict__ projh,
                                              ushort_t* __restrict__ projl,
                                              ushort_t* __restrict__ gT) {
    __shared__ ushort_t xT[2][64 * 256];   // [hi/lo][n][c], 64KB
    int b = blockIdx.y, n0 = blockIdx.x * 64;
    int tid = threadIdx.x;
    int w = tid >> 6, lane = tid & 63;
    int mrow = lane & 15, quad = lane >> 4, koff = quad * 8;
    int arow = w * 16 + mrow;

    for (int s = 0; s < 2; s++) {
        if (s) __syncthreads();            // all waves done with pass-0 LDS
        const float* src = s ? y : x;
        #pragma unroll
        for (int i = 0; i < 8; i++) {
            int ch = tid + i * 256;               // 2048 chunks
            int c = ch >> 3, off = (ch & 7) * 8;  // 8-elem chunk along n
            const float* p = src + (size_t)(b * 256 + c) * 4096 + n0 + off;
            float4v v0 = *(const float4v*)p;
            float4v v1 = *(const float4v*)(p + 4);
            #pragma unroll
            for (int jj = 0; jj < 4; jj++) {
                ushort_t h, l;
                split2(v0[jj], h, l);
                xT[0][(off + jj) * 256 + c] = h;
                xT[1][(off + jj) * 256 + c] = l;
                split2(v1[jj], h, l);
                xT[0][(off + 4 + jj) * 256 + c] = h;
                xT[1][(off + 4 + jj) * 256 + c] = l;
            }
        }
        __syncthreads();

        short8 fh[8], fl[8];
        #pragma unroll
        for (int kk = 0; kk < 8; kk++) {
            fh[kk] = *(const short8*)&xT[0][arow * 256 + kk * 32 + koff];
            fl[kk] = *(const short8*)&xT[1][arow * 256 + kk * 32 + koff];
        }

        int ot0 = s ? 8 : 0, ot1 = s ? 24 : 8;
        for (int ot = ot0; ot < ot1; ot++) {
            float4v acc = {0.f, 0.f, 0.f, 0.f};
            #pragma unroll
            for (int kk = 0; kk < 8; kk++) {
                short8 bh = *(const short8*)(wtfh + (size_t)((ot * 8 + kk) * 64 + lane) * 8);
                short8 bl = *(const short8*)(wtfl + (size_t)((ot * 8 + kk) * 64 + lane) * 8);
                acc = __builtin_amdgcn_mfma_f32_16x16x32_bf16(fh[kk], bh, acc, 0, 0, 0);
                acc = __builtin_amdgcn_mfma_f32_16x16x32_bf16(fh[kk], bl, acc, 0, 0, 0);
                acc = __builtin_amdgcn_mfma_f32_16x16x32_bf16(fl[kk], bh, acc, 0, 0, 0);
            }
            int o = ot * 16 + mrow;                  // C/D: col = lane&15
            float bo = bias[o];
            #pragma unroll
            for (int r = 0; r < 4; r++) {
                int n = n0 + w * 16 + quad * 4 + r;  // C/D: row = quad*4 + reg
                float v = acc[r] + bo;
                if (ot < 16) {
                    ushort_t h, l;
                    split2(v, h, l);
                    projh[(size_t)(b * 4096 + n) * 256 + o] = h;
                    projl[(size_t)(b * 4096 + n) * 256 + o] = l;
                } else {
                    gT[(size_t)(b * 128 + (o - 256)) * 4096 + n] = f2b(v);
                }
            }
        }
    }
}

// ============================================================================
// Kernel 3: flash attention, split-precision QK^T. Per block: (b, 64-row Q
// tile). S = Qh.Kh + Qh.Kl + Ql.Kh; online softmax in C-layout regs; P via
// LDS round-trip to A-layout (single bf16 — benign); O += P.V.
// ============================================================================
__global__ __launch_bounds__(256) void flash_k(const ushort_t* __restrict__ projh,
                                               const ushort_t* __restrict__ projl,
                                               const ushort_t* __restrict__ gT,
                                               ushort_t* __restrict__ y2h,
                                               ushort_t* __restrict__ y2l) {
    __shared__ __align__(16) ushort_t Ksh[64 * 136];  // [key][ic], pad 8
    __shared__ __align__(16) ushort_t Ksl[64 * 136];
    __shared__ __align__(16) ushort_t VsT[128 * 72];  // [ic][key], pad 8
    __shared__ __align__(16) ushort_t Ps[64 * 72];    // [qrow][key], pad 8
    int b = blockIdx.y, q0 = blockIdx.x * 64;
    int tid = threadIdx.x, w = tid >> 6, lane = tid & 63;
    int mrow = lane & 15, quad = lane >> 4, koff = quad * 8;

    short8 qfh[4], qfl[4];
    #pragma unroll
    for (int kk = 0; kk < 4; kk++) {
        size_t qoff = (size_t)(b * 4096 + q0 + w * 16 + mrow) * 256 + kk * 32 + koff;
        qfh[kk] = *(const short8*)(projh + qoff);
        qfl[kk] = *(const short8*)(projl + qoff);
    }

    float m_i[4], l_i[4];
    float4v oacc[8];
    #pragma unroll
    for (int r = 0; r < 4; r++) { m_i[r] = -INFINITY; l_i[r] = 0.f; }
    #pragma unroll
    for (int ot = 0; ot < 8; ot++) oacc[ot] = (float4v){0.f, 0.f, 0.f, 0.f};

    for (int kt = 0; kt < 64; kt++) {
        int kb = kt * 64;
        __syncthreads();
        #pragma unroll
        for (int i = 0; i < 4; i++) {              // K tile: phi cols (+128), hi+lo
            int ch = tid + i * 256;
            int kr = ch >> 4, off = (ch & 15) * 8;
            size_t goff = (size_t)(b * 4096 + kb + kr) * 256 + 128 + off;
            *(ushort8*)&Ksh[kr * 136 + off] = *(const ushort8*)(projh + goff);
            *(ushort8*)&Ksl[kr * 136 + off] = *(const ushort8*)(projl + goff);
        }
        #pragma unroll
        for (int i = 0; i < 4; i++) {              // V tile from gT: already [ic][n]
            int ch = tid + i * 256;
            int ic = ch >> 3, off = (ch & 7) * 8;
            ushort8 v = *(const ushort8*)(gT + (size_t)(b * 128 + ic) * 4096 + kb + off);
            *(ushort8*)&VsT[ic * 72 + off] = v;
        }
        __syncthreads();

        float4v sacc[4];
        #pragma unroll
        for (int ct = 0; ct < 4; ct++) {
            float4v acc = {0.f, 0.f, 0.f, 0.f};
            #pragma unroll
            for (int kk = 0; kk < 4; kk++) {
                int lo = (ct * 16 + mrow) * 136 + kk * 32 + koff;
                short8 bh = *(const short8*)&Ksh[lo];
                short8 bl = *(const short8*)&Ksl[lo];
                acc = __builtin_amdgcn_mfma_f32_16x16x32_bf16(qfh[kk], bh, acc, 0, 0, 0);
                acc = __builtin_amdgcn_mfma_f32_16x16x32_bf16(qfh[kk], bl, acc, 0, 0, 0);
                acc = __builtin_amdgcn_mfma_f32_16x16x32_bf16(qfl[kk], bh, acc, 0, 0, 0);
            }
            sacc[ct] = acc;
        }

        #pragma unroll
        for (int r = 0; r < 4; r++) {
            float mx = fmaxf(fmaxf(sacc[0][r], sacc[1][r]), fmaxf(sacc[2][r], sacc[3][r]));
            #pragma unroll
            for (int d = 1; d < 16; d <<= 1) mx = fmaxf(mx, __shfl_xor(mx, d, 64));
            float mnew = fmaxf(m_i[r], mx);
            float alpha = __expf(m_i[r] - mnew);   // first iter: exp(-inf) = 0
            m_i[r] = mnew;
            float rs = 0.f;
            #pragma unroll
            for (int ct = 0; ct < 4; ct++) {
                float p = __expf(sacc[ct][r] - mnew);
                sacc[ct][r] = p;
                rs += p;
            }
            #pragma unroll
            for (int d = 1; d < 16; d <<= 1) rs += __shfl_xor(rs, d, 64);
            l_i[r] = l_i[r] * alpha + rs;
            #pragma unroll
            for (int ot = 0; ot < 8; ot++) oacc[ot][r] *= alpha;
            int prow = w * 16 + quad * 4 + r;
            #pragma unroll
            for (int ct = 0; ct < 4; ct++) Ps[prow * 72 + ct * 16 + mrow] = f2b(sacc[ct][r]);
        }
        __syncthreads();

        #pragma unroll
        for (int ot = 0; ot < 8; ot++) {
            float4v acc = oacc[ot];
            #pragma unroll
            for (int k2 = 0; k2 < 2; k2++) {
                short8 afr = *(const short8*)&Ps[(w * 16 + mrow) * 72 + k2 * 32 + koff];
                short8 bfr = *(const short8*)&VsT[(ot * 16 + mrow) * 72 + k2 * 32 + koff];
                acc = __builtin_amdgcn_mfma_f32_16x16x32_bf16(afr, bfr, acc, 0, 0, 0);
            }
            oacc[ot] = acc;
        }
    }

    #pragma unroll
    for (int ot = 0; ot < 8; ot++) {
        int ic = ot * 16 + mrow;
        #pragma unroll
        for (int r = 0; r < 4; r++) {
            int n = q0 + w * 16 + quad * 4 + r;
            float v = oacc[ot][r] / l_i[r];
            ushort_t h, l;
            split2(v, h, l);
            y2h[(size_t)(b * 4096 + n) * 128 + ic] = h;
            y2l[(size_t)(b * 4096 + n) * 128 + ic] = l;
        }
    }
}

// ============================================================================
// Kernel 4: wy = w_w . y2^T + w_b, split precision (wh.yh + wh.yl + wl.yh).
// Write wy bf16 [b][co][n] + per-channel sum/sumsq (f32, pre-quantization)
// via shuffle-reduce -> LDS -> global atomics.
// ============================================================================
__global__ __launch_bounds__(256) void wy_k(const ushort_t* __restrict__ y2h,
                                            const ushort_t* __restrict__ y2l,
                                            const ushort_t* __restrict__ wwbh,
                                            const ushort_t* __restrict__ wwbl,
                                            const float* __restrict__ w_b,
                                            ushort_t* __restrict__ wy,
                                            float* __restrict__ stats) {
    __shared__ float s_sum[256], s_sq[256];
    int b = blockIdx.y, n0 = blockIdx.x * 64;
    int tid = threadIdx.x, w = tid >> 6, lane = tid & 63;
    s_sum[tid] = 0.f; s_sq[tid] = 0.f;
    __syncthreads();
    int mrow = lane & 15, quad = lane >> 4, koff = quad * 8;

    short8 bfh[4], bfl[4];   // B-frags: y2 rows contiguous [n][ic]
    #pragma unroll
    for (int kk = 0; kk < 4; kk++) {
        size_t yoff = (size_t)(b * 4096 + n0 + w * 16 + mrow) * 128 + kk * 32 + koff;
        bfh[kk] = *(const short8*)(y2h + yoff);
        bfl[kk] = *(const short8*)(y2l + yoff);
    }

    int coln = n0 + w * 16 + mrow;
    for (int cot = 0; cot < 16; cot++) {
        float4v acc = {0.f, 0.f, 0.f, 0.f};
        #pragma unroll
        for (int kk = 0; kk < 4; kk++) {
            size_t woff = (size_t)(cot * 16 + mrow) * 128 + kk * 32 + koff;
            short8 ah = *(const short8*)(wwbh + woff);
            short8 al = *(const short8*)(wwbl + woff);
            acc = __builtin_amdgcn_mfma_f32_16x16x32_bf16(ah, bfh[kk], acc, 0, 0, 0);
            acc = __builtin_amdgcn_mfma_f32_16x16x32_bf16(ah, bfl[kk], acc, 0, 0, 0);
            acc = __builtin_amdgcn_mfma_f32_16x16x32_bf16(al, bfh[kk], acc, 0, 0, 0);
        }
        #pragma unroll
        for (int r = 0; r < 4; r++) {
            int co = cot * 16 + quad * 4 + r;
            float v = acc[r] + w_b[co];
            wy[(size_t)(b * 256 + co) * 4096 + coln] = f2b(v);
            float sv = v, sq = v * v;
            #pragma unroll
            for (int d = 1; d < 16; d <<= 1) {
                sv += __shfl_xor(sv, d, 64);
                sq += __shfl_xor(sq, d, 64);
            }
            if (mrow == 0) { atomicAdd(&s_sum[co], sv); atomicAdd(&s_sq[co], sq); }
        }
    }
    __syncthreads();
    atomicAdd(&stats[tid], s_sum[tid]);
    atomicAdd(&stats[256 + tid], s_sq[tid]);
}

// ============================================================================
// Kernel 5: BN (training-mode batch stats, biased var, eps=1e-5) + residual.
// out[b][c][n] = gamma[c]*(wy-mean)/sqrt(var+eps) + beta[c] + x, f32 out.
// ============================================================================
__global__ __launch_bounds__(256) void bn_k(const ushort_t* __restrict__ wy,
                                            const float* __restrict__ x,
                                            const float* __restrict__ gamma,
                                            const float* __restrict__ beta,
                                            const float* __restrict__ stats,
                                            float* __restrict__ out) {
    int idx = (blockIdx.x * 256 + threadIdx.x) * 8;     // B*C*N = 1<<22
    int c = (idx >> 12) & 255;
    const float inv_cnt = 1.f / 16384.f;                // B*H*W samples per channel
    float mean = stats[c] * inv_cnt;
    float var  = stats[256 + c] * inv_cnt - mean * mean;
    float inv  = rsqrtf(var + 1e-5f);
    float scale = gamma[c] * inv;
    float shift = beta[c] - mean * scale;
    ushort8 wv = *(const ushort8*)(wy + idx);
    float4v x0 = *(const float4v*)(x + idx);
    float4v x1 = *(const float4v*)(x + idx + 4);
    float4v o0, o1;
    #pragma unroll
    for (int j = 0; j < 4; j++) {
        o0[j] = b2f(wv[j]) * scale + shift + x0[j];
        o1[j] = b2f(wv[4 + j]) * scale + shift + x1[j];
    }
    *(float4v*)(out + idx) = o0;
    *(float4v*)(out + idx + 4) = o1;
}

extern "C" void kernel_launch(void* const* d_in, const int* in_sizes, int n_in,
                              void* d_out, int out_size, void* d_ws, size_t ws_size,
                              hipStream_t stream) {
    const float* x    = (const float*)d_in[0];
    const float* y    = (const float*)d_in[1];
    const float* g_w  = (const float*)d_in[2];
    const float* g_b  = (const float*)d_in[3];
    const float* dx_w = (const float*)d_in[4];
    const float* dx_b = (const float*)d_in[5];
    const float* dy_w = (const float*)d_in[6];
    const float* dy_b = (const float*)d_in[7];
    const float* w_w  = (const float*)d_in[8];
    const float* w_b  = (const float*)d_in[9];
    const float* bn_g = (const float*)d_in[10];
    const float* bn_b = (const float*)d_in[11];

    char* ws = (char*)d_ws;
    ushort_t* wtfh  = (ushort_t*)(ws + WTFH_OFF);
    ushort_t* wtfl  = (ushort_t*)(ws + WTFL_OFF);
    ushort_t* wwbh  = (ushort_t*)(ws + WWBH_OFF);
    ushort_t* wwbl  = (ushort_t*)(ws + WWBL_OFF);
    float*    bias  = (float*)(ws + BIAS_OFF);
    float*    stats = (float*)(ws + STATS_OFF);
    ushort_t* projh = (ushort_t*)(ws + PROJH_OFF);
    ushort_t* projl = (ushort_t*)(ws + PROJL_OFF);
    ushort_t* gT    = (ushort_t*)(ws + GT_OFF);
    ushort_t* y2h   = (ushort_t*)(ws + Y2H_OFF);
    ushort_t* y2l   = (ushort_t*)(ws + Y2L_OFF);
    ushort_t* wy    = (ushort_t*)(ws + WY_OFF);
    float*    out   = (float*)d_out;

    prep_k<<<384, 256, 0, stream>>>(dx_w, dy_w, g_w, dx_b, dy_b, g_b, w_w,
                                    wtfh, wtfl, wwbh, wwbl, bias, stats);
    proj_k<<<dim3(64, 4), 256, 0, stream>>>(x, y, wtfh, wtfl, bias, projh, projl, gT);
    flash_k<<<dim3(64, 4), 256, 0, stream>>>(projh, projl, gT, y2h, y2l);
    wy_k<<<dim3(64, 4), 256, 0, stream>>>(y2h, y2l, wwbh, wwbl, w_b, wy, stats);
    bn_k<<<2048, 256, 0, stream>>>(wy, x, bn_g, bn_b, stats, out);
}